// Round 11
// baseline (168.150 us; speedup 1.0000x reference)
//
#include <hip/hip_runtime.h>

typedef short short8 __attribute__((ext_vector_type(8)));
typedef float f32x4  __attribute__((ext_vector_type(4)));

constexpr int M_TOT  = 8 * 4096;   // 32768 pixels
constexpr int K_PROT = 1024;
constexpr int D_DIM  = 128;

// ws layout: psq @0 (4 KB), pfrag @4K (256 KB)
constexpr size_t WS_PF_OFF = (size_t)K_PROT * 4;

constexpr int PSQ_BLOCKS   = K_PROT / 8;    // 128
constexpr int PFRAG_BLOCKS = 16384 / 256;   // 64

__device__ inline unsigned short bf16_rne(float f) {
  unsigned u = __builtin_bit_cast(unsigned, f);
  unsigned r = u + 0x7FFFu + ((u >> 16) & 1u);   // RNE
  return (unsigned short)(r >> 16);
}

// LDS-only barrier: ds ops complete (lgkmcnt), but do NOT drain in-flight
// global stores (vmcnt) like __syncthreads() would.
__device__ inline void barrier_lds() {
  asm volatile("s_waitcnt lgkmcnt(0)\n\ts_barrier" ::: "memory");
}

// ---------------------------------------------------------------------------
// Prep: psq blocks [0,128); pfrag [128,192).
// pf (single bf16): g in [0,16384): ng=g>>8 (16-proto group), ks=(g>>6)&3,
// lane=g&63. proto = ng*16 + (lane&15), k = ks*32 + (lane>>4)*8 + j.
__global__ __launch_bounds__(256) void prep_kernel(
    const float* __restrict__ p, float* __restrict__ psq,
    short* __restrict__ pf) {
  const int bx  = blockIdx.x;
  const int tid = threadIdx.x;
  if (bx < PSQ_BLOCKS) {
    int group = bx * 8 + (tid >> 5);
    int lane  = tid & 31;
    if (group >= K_PROT) return;
    float4 v = reinterpret_cast<const float4*>(p + (size_t)group * D_DIM)[lane];
    float s = v.x * v.x + v.y * v.y + v.z * v.z + v.w * v.w;
    #pragma unroll
    for (int off = 16; off > 0; off >>= 1) s += __shfl_down(s, off, 32);
    if (lane == 0) psq[group] = s;
  } else {
    int g    = (bx - PSQ_BLOCKS) * 256 + tid;   // 0..16383
    int lane = g & 63;
    int ks   = (g >> 6) & 3;
    int ng   = g >> 8;
    int proto = ng * 16 + (lane & 15);
    int k0    = ks * 32 + (lane >> 4) * 8;
    const float4* pr = (const float4*)(p + (size_t)proto * D_DIM + k0);
    float4 a = pr[0], b = pr[1];
    float e[8] = {a.x, a.y, a.z, a.w, b.x, b.y, b.z, b.w};
    short8 frag;
    #pragma unroll
    for (int j = 0; j < 8; ++j) frag[j] = (short)bf16_rne(e[j]);
    *(short8*)(pf + (size_t)g * 8) = frag;
  }
}

// ---------------------------------------------------------------------------
// Main: A=protos (pf via L2, lockstep -> L2-resident), B=pixels (LDS).
// R11 = R10 (64 pix/block, 512 threads, 8 waves, lockstep) with BUFFER-ROTATED
// staging: four 64-col rounds per chunk alternate between two 17 KB buffers,
// ONE barrier per round. Each drain (ds_read + global stores) overlaps the
// NEXT round's stage — and the last drain overlaps the next chunk's pf loads
// and MFMAs — so stores retire during compute instead of stalling all waves
// between back-to-back barriers (the serialization left in R10: 2.8 TB/s
// combined, far under the 6.3 achievable => latency- not BW-bound).
// Hazard: writer of buf X at round r+2 is separated from its reader (drain r)
// by barrier r+1; barrier_lds's lgkmcnt(0) completes drain ds_reads there.
// C/D: col(lane&15)=pixel, row=(lane>>4)*4+reg = 4 consecutive protos.
__global__ __launch_bounds__(512, 4) void proto_mfma(
    const float* __restrict__ x, const float* __restrict__ p,
    const short* __restrict__ pf, const float* __restrict__ psq,
    float* __restrict__ matched, float* __restrict__ scores) {
  __shared__ short xlds[16 * 64 * 8];   // 16 KB: [nt*4 + ks][lane][8]
  __shared__ float sbuf[2][64][68];     // 2 x 17.4 KB rotating staging buffers
  __shared__ float sv[8][64];
  __shared__ int   si[8][64];
  __shared__ int   fidx[64];
  __shared__ float xsqv[64];

  const int tid  = threadIdx.x;
  const int w    = tid >> 6;            // 0..7
  const int l    = tid & 63;
  const int m0   = blockIdx.x * 64;
  const int csub = (l >> 4) << 2;       // 0,4,8,12

  // xpart alias: [pixel 0..63][16 partials] = 4 KB inside sbuf[0] (unused yet)
  float (*xpart)[16] = (float(*)[16])&sbuf[0][0][0];

  // ---- stage x tile into LDS in B-fragment order + xsq partials (once) ----
  #pragma unroll
  for (int i = 0; i < 2; ++i) {
    int piece = i * 512 + tid;          // 0..1023
    int s = piece >> 6;                 // 0..15
    int ks = s & 3, nt = s >> 2;
    int pix = m0 + nt * 16 + (l & 15);
    int k0  = ks * 32 + (l >> 4) * 8;
    const float4* xr = (const float4*)(x + (size_t)pix * D_DIM + k0);
    float4 a = xr[0], b = xr[1];
    float e[8] = {a.x, a.y, a.z, a.w, b.x, b.y, b.z, b.w};
    float ss = e[0]*e[0] + e[1]*e[1] + e[2]*e[2] + e[3]*e[3]
             + e[4]*e[4] + e[5]*e[5] + e[6]*e[6] + e[7]*e[7];
    xpart[nt * 16 + (l & 15)][ks * 4 + (l >> 4)] = ss;
    short8 frag;
    #pragma unroll
    for (int j = 0; j < 8; ++j) frag[j] = (short)bf16_rne(e[j]);
    *(short8*)(xlds + (size_t)piece * 8) = frag;
  }
  __syncthreads();

  if (tid < 64) {
    float s = 0.f;
    #pragma unroll
    for (int j = 0; j < 16; ++j) s += xpart[tid][j];
    xsqv[tid] = s;
  }
  __syncthreads();   // xsqv ready; sbuf free for score staging after this

  float xs[4];
  #pragma unroll
  for (int nt = 0; nt < 4; ++nt) xs[nt] = xsqv[nt * 16 + (l & 15)];

  float best[4]; int bidx[4];
  #pragma unroll
  for (int nt = 0; nt < 4; ++nt) { best[nt] = -3.4e38f; bidx[nt] = 0; }

  for (int chunk = 0; chunk < 4; ++chunk) {
    f32x4 acc[2][4];
    #pragma unroll
    for (int mt = 0; mt < 2; ++mt)
      #pragma unroll
      for (int nt = 0; nt < 4; ++nt) acc[mt][nt] = (f32x4){0.f, 0.f, 0.f, 0.f};

    const int pgbase = chunk * 16 + w * 2;

    #pragma unroll
    for (int ks = 0; ks < 4; ++ks) {
      short8 pah[2], bh[4];
      #pragma unroll
      for (int mt = 0; mt < 2; ++mt)
        pah[mt] = *(const short8*)(pf + ((size_t)((pgbase + mt) * 4 + ks) * 64 + l) * 8);
      #pragma unroll
      for (int nt = 0; nt < 4; ++nt)
        bh[nt] = *(const short8*)(xlds + (size_t)(((nt * 4 + ks) * 64) + l) * 8);
      #pragma unroll
      for (int mt = 0; mt < 2; ++mt)
        #pragma unroll
        for (int nt = 0; nt < 4; ++nt)
          acc[mt][nt] = __builtin_amdgcn_mfma_f32_16x16x32_bf16(pah[mt], bh[nt], acc[mt][nt], 0, 0, 0);
    }

    // ---- transform acc in place to final score values + running argmax ----
    #pragma unroll
    for (int mt = 0; mt < 2; ++mt) {
      int pbase = chunk * 256 + w * 32 + mt * 16 + csub;
      float psa[4];
      *(float4*)psa = *(const float4*)(psq + pbase);
      #pragma unroll
      for (int nt = 0; nt < 4; ++nt) {
        f32x4 o;
        {
          #pragma clang fp contract(off)
          #pragma unroll
          for (int r = 0; r < 4; ++r) {
            float t = (xs[nt] + psa[r]) - 2.0f * acc[mt][nt][r];
            o[r] = -t;
            if (o[r] > best[nt]) { best[nt] = o[r]; bidx[nt] = pbase + r; }
          }
        }
        acc[mt][nt] = o;   // acc now holds final scores
      }
    }

    // ---- 4 buffer-rotated rounds: stage -> ONE barrier -> drain (overlapped
    //      with next round's stage / next chunk's compute) ----
    #pragma unroll
    for (int rnd = 0; rnd < 4; ++rnd) {
      float (*buf)[68] = sbuf[rnd & 1];
      if ((w >> 1) == rnd) {
        const int colbase = (w & 1) * 32 + csub;
        #pragma unroll
        for (int mt = 0; mt < 2; ++mt)
          #pragma unroll
          for (int nt = 0; nt < 4; ++nt)
            *(f32x4*)&buf[nt * 16 + (l & 15)][colbase + mt * 16] = acc[mt][nt];
      }
      barrier_lds();
      const int gbase = chunk * 256 + rnd * 64;
      #pragma unroll
      for (int ps = 0; ps < 2; ++ps) {
        int idx = ps * 512 + tid;    // 0..1023
        int row = idx >> 4;          // 0..63 (16 f32x4 per row)
        int c4  = idx & 15;          // 0..15 (64 cols / 4)
        f32x4 v = *(const f32x4*)&buf[row][c4 * 4];
        *((f32x4*)(scores + (size_t)(m0 + row) * K_PROT + gbase) + c4) = v;
      }
      // no trailing barrier: next round writes the OTHER buffer; the next
      // writer of THIS buffer (rnd+2) is fenced by barrier rnd+1.
    }
  }

  // ---- argmax reduce: butterfly over quads, then LDS over waves ----
  #pragma unroll
  for (int nt = 0; nt < 4; ++nt) {
    #pragma unroll
    for (int m = 16; m <= 32; m <<= 1) {
      float ov = __shfl_xor(best[nt], m);
      int   oi = __shfl_xor(bidx[nt], m);
      if (ov > best[nt] || (ov == best[nt] && oi < bidx[nt])) {
        best[nt] = ov; bidx[nt] = oi;
      }
    }
  }
  __syncthreads();   // all drains done; sv/si region safe (fresh arrays anyway)
  if (l < 16) {
    #pragma unroll
    for (int nt = 0; nt < 4; ++nt) {
      sv[w][nt * 16 + l] = best[nt];
      si[w][nt * 16 + l] = bidx[nt];
    }
  }
  __syncthreads();
  if (tid < 64) {
    float v = sv[0][tid]; int bi = si[0][tid];
    #pragma unroll
    for (int e = 1; e < 8; ++e) {
      float vv = sv[e][tid]; int ii = si[e][tid];
      if (vv > v || (vv == v && ii < bi)) { v = vv; bi = ii; }
    }
    fidx[tid] = bi;
  }
  __syncthreads();

  // ---- gather matched = original fp32 prototypes[argmax] ----
  #pragma unroll
  for (int q0 = 0; q0 < 4; ++q0) {
    int q = q0 * 512 + tid;          // 0..2047
    int pix = q >> 5, f4 = q & 31;
    float4 v = ((const float4*)(p + (size_t)fidx[pix] * D_DIM))[f4];
    *((f32x4*)(matched + (size_t)(m0 + pix) * D_DIM) + f4) = *(f32x4*)&v;
  }
}

// ---------------------------------------------------------------------------
extern "C" void kernel_launch(void* const* d_in, const int* in_sizes, int n_in,
                              void* d_out, int out_size, void* d_ws, size_t ws_size,
                              hipStream_t stream) {
  const float* x = (const float*)d_in[0];   // [B,N,D] fp32
  const float* p = (const float*)d_in[1];   // [K,D]   fp32

  float* matched = (float*)d_out;                            // [B,N,D]
  float* scores  = (float*)d_out + (size_t)M_TOT * D_DIM;    // [B,N,K]

  float* psq = (float*)d_ws;
  short* pf  = (short*)((char*)d_ws + WS_PF_OFF);

  prep_kernel<<<PSQ_BLOCKS + PFRAG_BLOCKS, 256, 0, stream>>>(p, psq, pf);
  proto_mfma<<<M_TOT / 64, 512, 0, stream>>>(x, p, pf, psq, matched, scores);
}